// Round 9
// baseline (95.023 us; speedup 1.0000x reference)
//
#include <hip/hip_runtime.h>

typedef __bf16 bf16_t;
typedef __bf16 bf16x8 __attribute__((ext_vector_type(8)));
typedef float f32x4 __attribute__((ext_vector_type(4)));

#define GK 768   // inner K dim for every GEMM in this problem

// ---------------- workspace layout (bytes) ----------------
static constexpr size_t OFF_WT_QKV = 0;                                  // [2304][768] bf16
static constexpr size_t OFF_WT_CAR  = OFF_WT_QKV + (size_t)2304*768*2;   // [768][768] bf16
static constexpr size_t OFF_WT_PROJ = OFF_WT_CAR + (size_t)768*768*2;    // [768][768] bf16
static constexpr size_t OFF_WMEAN   = OFF_WT_PROJ + (size_t)768*768*2;   // [256][768] bf16
static constexpr size_t OFF_CARP    = OFF_WMEAN + (size_t)256*768*2;     // [4][256][768] f32 split-K partials
static constexpr size_t OFF_LN      = OFF_CARP + (size_t)4*256*768*4;    // [5120][768] bf16
static constexpr size_t OFF_QKV     = OFF_LN + (size_t)5120*768*2;       // [5120][2304] bf16 (q|k|v)
static constexpr size_t OFF_CTX     = OFF_QKV + (size_t)5120*2304*2;     // [2][2048][768] bf16
static constexpr size_t OFF_NOP     = OFF_CTX + (size_t)2*2048*768*2;    // 64B scratch for nop probe

// ---------------- async global->LDS (16B per lane) ----------------
__device__ __forceinline__ void gload16(const bf16_t* g, bf16_t* lds_wave_base) {
  __builtin_amdgcn_global_load_lds(
      (const __attribute__((address_space(1))) unsigned int*)g,
      (__attribute__((address_space(3))) unsigned int*)lds_wave_base,
      16, 0, 0);
}

// ---------------- fused prep: 3 weight transposes (fp32->bf16, W[K][N]->Wt[N][K]) + window means ----------------
__global__ __launch_bounds__(256) void prep_kernel(const float* __restrict__ W_qkv,
                                                   const float* __restrict__ W_car,
                                                   const float* __restrict__ W_proj,
                                                   const float* __restrict__ x,
                                                   bf16_t* __restrict__ wt_qkv,
                                                   bf16_t* __restrict__ wt_car,
                                                   bf16_t* __restrict__ wt_proj,
                                                   bf16_t* __restrict__ wm) {
  int bid = blockIdx.x;
  if (bid < 2880) {
    __shared__ float tile[32][33];
    const float* W; bf16_t* Wt; int Ndim, kb, nb;
    if (bid < 1728) {
      W = W_qkv; Wt = wt_qkv; Ndim = 2304; kb = (bid % 24) * 32; nb = (bid / 24) * 32;
    } else if (bid < 2304) {
      int q = bid - 1728; W = W_car; Wt = wt_car; Ndim = 768; kb = (q % 24) * 32; nb = (q / 24) * 32;
    } else {
      int q = bid - 2304; W = W_proj; Wt = wt_proj; Ndim = 768; kb = (q % 24) * 32; nb = (q / 24) * 32;
    }
    int tx = threadIdx.x & 31, ty = threadIdx.x >> 5;   // ty in 0..7
    #pragma unroll
    for (int i = 0; i < 32; i += 8)
      tile[ty + i][tx] = W[(size_t)(kb + ty + i) * Ndim + nb + tx];
    __syncthreads();
    #pragma unroll
    for (int i = 0; i < 32; i += 8)
      Wt[(size_t)(nb + ty + i) * GK + kb + tx] = (bf16_t)tile[tx][ty + i];
  } else {
    int w = bid - 2880;            // 0..255  (b*128 + window)
    int b = w >> 7, ww = w & 127;
    const float* base = x + ((size_t)b * 2048 + (size_t)ww * 16) * 768;
    for (int d = threadIdx.x; d < 768; d += 256) {
      float s = 0.f;
      #pragma unroll
      for (int i = 0; i < 16; i++) s += base[(size_t)i * 768 + d];
      wm[(size_t)w * 768 + d] = (bf16_t)(s * (1.f / 16.f));
    }
  }
}

// ---------------- 64x128-tile bf16 MFMA GEMM, split-K (carrier GEMM only) ----------------
__global__ __launch_bounds__(256) void gemm64_kernel(const bf16_t* __restrict__ A,
                                                     const bf16_t* __restrict__ Bt,
                                                     float* __restrict__ outF,
                                                     int mB, int nB, int kspan) {
  __shared__ __align__(16) bf16_t As[64 * 32];
  __shared__ __align__(16) bf16_t Bs[128 * 32];
  int bid = blockIdx.x;
  int bm = bid % mB;
  int rest = bid / mB;
  int bn = rest % nB;
  int kz = rest / nB;
  int t = threadIdx.x, wid = t >> 6, lane = t & 63;
  int wm = wid >> 1, wn = wid & 1;
  int sr = t >> 2, sk = (t & 3) * 8;
  const bf16_t* gA = A + (size_t)(bm * 64 + sr) * GK + sk;
  const bf16_t* gB = Bt + (size_t)(bn * 128 + sr) * GK + sk;
  bf16_t* lA  = As + wid * 512;
  bf16_t* lB0 = Bs + wid * 512;
  bf16_t* lB1 = Bs + 2048 + wid * 512;
  int fr = lane & 15, fk = (lane >> 4) * 8;

  f32x4 acc[2][4] = {};
  int k0 = kz * kspan, kend = k0 + kspan;
  for (; k0 < kend; k0 += 32) {
    gload16(gA + k0,           lA);
    gload16(gB + k0,           lB0);
    gload16(gB + k0 + 64 * GK, lB1);
    __syncthreads();
    bf16x8 af[2], bfr[4];
    #pragma unroll
    for (int i = 0; i < 2; i++)
      af[i] = *(const bf16x8*)(As + (wm * 32 + i * 16 + fr) * 32 + fk);
    #pragma unroll
    for (int j = 0; j < 4; j++)
      bfr[j] = *(const bf16x8*)(Bs + (wn * 64 + j * 16 + fr) * 32 + fk);
    #pragma unroll
    for (int i = 0; i < 2; i++)
      #pragma unroll
      for (int j = 0; j < 4; j++)
        acc[i][j] = __builtin_amdgcn_mfma_f32_16x16x32_bf16(af[i], bfr[j], acc[i][j], 0, 0, 0);
    __syncthreads();
  }

  #pragma unroll
  for (int i = 0; i < 2; i++) {
    int rbase = bm * 64 + wm * 32 + i * 16 + ((lane >> 4) << 2);
    #pragma unroll
    for (int j = 0; j < 4; j++) {
      int col = bn * 128 + wn * 64 + j * 16 + (lane & 15);
      f32x4 a = acc[i][j];
      #pragma unroll
      for (int r = 0; r < 4; r++)
        outF[(size_t)kz * 196608 + (size_t)(rbase + r) * 768 + col] = a[r];
    }
  }
}

// ---------------- fused LayerNorm over "combined" rows -> bf16 ----------------
__global__ __launch_bounds__(256) void ln_kernel(const float* __restrict__ x,
                                                 const float* __restrict__ carP,
                                                 const float* __restrict__ b_car,
                                                 const float* __restrict__ gamma,
                                                 const float* __restrict__ beta,
                                                 bf16_t* __restrict__ out) {
  __shared__ float red[8];
  int row = blockIdx.x;                 // 0 .. 5119
  int b = row / 2560, n = row - b * 2560;
  int t = threadIdx.x;
  float v0, v1, v2;
  if (n < 2048) {
    const float* src = x + ((size_t)b * 2048 + n) * 768;
    v0 = src[t]; v1 = src[t + 256]; v2 = src[t + 512];
  } else {
    size_t ci = (size_t)(b * 128 + ((n - 2048) >> 2)) * 768;
    const float* p0 = carP + ci;
    const float* p1 = carP + ci + 196608;
    const float* p2 = carP + ci + 2 * 196608;
    const float* p3 = carP + ci + 3 * 196608;
    v0 = p0[t]       + p1[t]       + p2[t]       + p3[t]       + b_car[t];
    v1 = p0[t + 256] + p1[t + 256] + p2[t + 256] + p3[t + 256] + b_car[t + 256];
    v2 = p0[t + 512] + p1[t + 512] + p2[t + 512] + p3[t + 512] + b_car[t + 512];
  }
  float s = v0 + v1 + v2;
  float q = v0 * v0 + v1 * v1 + v2 * v2;
  #pragma unroll
  for (int o = 32; o > 0; o >>= 1) { s += __shfl_down(s, o); q += __shfl_down(q, o); }
  int wv = t >> 6;
  if ((t & 63) == 0) { red[wv] = s; red[4 + wv] = q; }
  __syncthreads();
  s = red[0] + red[1] + red[2] + red[3];
  q = red[4] + red[5] + red[6] + red[7];
  float mean = s * (1.f / 768.f);
  float var  = q * (1.f / 768.f) - mean * mean;
  float rstd = rsqrtf(var + 1e-5f);
  bf16_t* o0 = out + (size_t)row * 768;
  o0[t]       = (bf16_t)((v0 - mean) * rstd * gamma[t]       + beta[t]);
  o0[t + 256] = (bf16_t)((v1 - mean) * rstd * gamma[t + 256] + beta[t + 256]);
  o0[t + 512] = (bf16_t)((v2 - mean) * rstd * gamma[t + 512] + beta[t + 512]);
}

// ---------------- QKV GEMM: 256x256 tile, BK=32, 3-slot ring, counted vmcnt (R7, best) ----------------
__global__ __launch_bounds__(512, 1) void gemm256_qkv(const bf16_t* __restrict__ A,
                                                      const bf16_t* __restrict__ Bt,
                                                      const float* __restrict__ bias,
                                                      bf16_t* __restrict__ qkv) {
  __shared__ __align__(16) bf16_t smem[3][2][8192];   // [slot][A=0/B=1][r*32 + swz]

  // bijective XCD swizzle (m204): nwg=180, xcd 0..3 get 23 blocks, 4..7 get 22
  int xcd = blockIdx.x & 7, idx = blockIdx.x >> 3;
  int wgid = (xcd < 4 ? xcd * 23 : 92 + (xcd - 4) * 22) + idx;
  int bm = wgid / 9, bn = wgid % 9;

  int t = threadIdx.x;
  int w = t >> 6, lane = t & 63;
  int wm = w >> 2, wn = w & 3;          // wm: 128-row band, wn: 64-col band
  int fr = lane & 15, s16 = lane >> 4;

  const bf16_t* Ab = A  + (size_t)bm * 256 * GK;
  const bf16_t* Bb = Bt + (size_t)bn * 256 * GK;

  const int srow  = t >> 2;                              // 0..127
  const int skoff = (((t & 3) ^ ((t >> 3) & 3)) << 3);   // inverse-swizzled k-elem offset
  const int wbase = w * 512;                             // wave-uniform dest (HW adds lane*16B)

  auto stageT = [&](const bf16_t* src, int mat, int T, int s) {
    const bf16_t* g = src + (size_t)srow * GK + T * 32 + skoff;
    gload16(g,            &smem[s][mat][wbase]);
    gload16(g + 128 * GK, &smem[s][mat][4096 + wbase]);
  };
  auto rdA = [&](int s, int m) -> bf16x8 {
    int r = wm * 128 + m * 16 + fr;
    return *(const bf16x8*)(&smem[s][0][r * 32 + ((s16 ^ ((r >> 1) & 3)) << 3)]);
  };
  auto rdB = [&](int s, int n) -> bf16x8 {
    int r = wn * 64 + n * 16 + fr;
    return *(const bf16x8*)(&smem[s][1][r * 32 + ((s16 ^ ((r >> 1) & 3)) << 3)]);
  };

  f32x4 acc[8][4] = {};

  // prologue: tile 0 -> slot 0, tile 1 -> slot 1 (each wave: 8 loads)
  stageT(Ab, 0, 0, 0); stageT(Bb, 1, 0, 0);
  stageT(Ab, 0, 1, 1); stageT(Bb, 1, 1, 1);
  asm volatile("s_waitcnt vmcnt(4)" ::: "memory");   // tile 0 landed; tile 1's 4 in flight
  __builtin_amdgcn_s_barrier();

  int s = 0, s2 = 2;
  #pragma unroll 3
  for (int T = 0; T < 24; ++T) {
    const bool pf = (T <= 21);
    bf16x8 bfr[4], a0[4], a1[4];
    { // ---- q0: read B n0-3 + A m0-3; stage A(T+2); MFMA m0-3 ----
      #pragma unroll
      for (int n = 0; n < 4; n++) bfr[n] = rdB(s, n);
      #pragma unroll
      for (int m = 0; m < 4; m++) a0[m] = rdA(s, m);
      if (pf) stageT(Ab, 0, T + 2, s2);
      __builtin_amdgcn_s_setprio(1);
      #pragma unroll
      for (int m = 0; m < 4; m++)
        #pragma unroll
        for (int n = 0; n < 4; n++)
          acc[m][n] = __builtin_amdgcn_mfma_f32_16x16x32_bf16(a0[m], bfr[n], acc[m][n], 0, 0, 0);
      __builtin_amdgcn_s_setprio(0);
      __builtin_amdgcn_s_barrier();
    }
    { // ---- q1: read A m4-7; stage B(T+2); MFMA m4-7; tile-boundary wait ----
      #pragma unroll
      for (int m = 0; m < 4; m++) a1[m] = rdA(s, 4 + m);
      if (pf) stageT(Bb, 1, T + 2, s2);
      __builtin_amdgcn_s_setprio(1);
      #pragma unroll
      for (int m = 0; m < 4; m++)
        #pragma unroll
        for (int n = 0; n < 4; n++)
          acc[4 + m][n] = __builtin_amdgcn_mfma_f32_16x16x32_bf16(a1[m], bfr[n], acc[4 + m][n], 0, 0, 0);
      __builtin_amdgcn_s_setprio(0);
      if (pf)            asm volatile("s_waitcnt vmcnt(4)" ::: "memory");  // T+1 landed, T+2 in flight
      else if (T == 22)  asm volatile("s_waitcnt vmcnt(0)" ::: "memory");  // drain for last tile
      __builtin_amdgcn_s_barrier();
    }
    s  = (s  == 2) ? 0 : s  + 1;
    s2 = (s2 == 2) ? 0 : s2 + 1;
  }

  // epilogue: D layout col = lane&15, row = (lane>>4)*4 + reg; plain row-major store
  #pragma unroll
  for (int m = 0; m < 8; m++) {
    int rbase = bm * 256 + wm * 128 + m * 16 + (s16 << 2);
    #pragma unroll
    for (int n = 0; n < 4; n++) {
      int col = bn * 256 + wn * 64 + n * 16 + fr;
      float bcol = bias[col];
      float sc = (col < 768) ? 0.125f : 1.f;   // fold SCALE into q section
      f32x4 a = acc[m][n];
      #pragma unroll
      for (int r2 = 0; r2 < 4; r2++)
        qkv[(size_t)(rbase + r2) * 2304 + col] = (bf16_t)((a[r2] + bcol) * sc);
    }
  }
}

// ---------------- 128x128 proj GEMM (R4-verified body, fp32+bias epilogue) ----------------
__global__ __launch_bounds__(256) void gemm128_proj(const bf16_t* __restrict__ A,
                                                    const bf16_t* __restrict__ Bt,
                                                    const float* __restrict__ bias,
                                                    float* __restrict__ outF) {
  __shared__ __align__(16) bf16_t As[128 * 32];
  __shared__ __align__(16) bf16_t Bs[128 * 32];

  int bm = blockIdx.x % 32;           // M = 4096
  int bn = blockIdx.x / 32;           // N = 768 -> 6 tiles
  int t = threadIdx.x;
  int wid = t >> 6, lane = t & 63;
  int wm = wid >> 1, wn = wid & 1;

  int sr = t >> 2;
  int sk = (t & 3) * 8;
  const bf16_t* gA = A + ((size_t)(bm * 128 + sr)) * GK + sk;
  const bf16_t* gB = Bt + ((size_t)(bn * 128 + sr)) * GK + sk;
  bf16_t* lA0 = As + wid * 512;
  bf16_t* lA1 = As + 2048 + wid * 512;
  bf16_t* lB0 = Bs + wid * 512;
  bf16_t* lB1 = Bs + 2048 + wid * 512;

  int fr = lane & 15;
  int fk = (lane >> 4) * 8;

  f32x4 acc[4][4] = {};

  for (int k0 = 0; k0 < GK; k0 += 32) {
    gload16(gA + k0,            lA0);
    gload16(gA + k0 + 64 * GK,  lA1);
    gload16(gB + k0,            lB0);
    gload16(gB + k0 + 64 * GK,  lB1);
    __syncthreads();
    bf16x8 af[4], bfr[4];
    #pragma unroll
    for (int i = 0; i < 4; i++)
      af[i] = *(const bf16x8*)(As + (wm * 64 + i * 16 + fr) * 32 + fk);
    #pragma unroll
    for (int i = 0; i < 4; i++)
      bfr[i] = *(const bf16x8*)(Bs + (wn * 64 + i * 16 + fr) * 32 + fk);
    #pragma unroll
    for (int i = 0; i < 4; i++)
      #pragma unroll
      for (int j = 0; j < 4; j++)
        acc[i][j] = __builtin_amdgcn_mfma_f32_16x16x32_bf16(af[i], bfr[j], acc[i][j], 0, 0, 0);
    __syncthreads();
  }

  #pragma unroll
  for (int i = 0; i < 4; i++) {
    int rbase = bm * 128 + wm * 64 + i * 16 + ((lane >> 4) << 2);
    #pragma unroll
    for (int j = 0; j < 4; j++) {
      int col = bn * 128 + wn * 64 + j * 16 + (lane & 15);
      float bcol = bias[col];
      f32x4 a = acc[i][j];
      #pragma unroll
      for (int r = 0; r < 4; r++)
        outF[(size_t)(rbase + r) * 768 + col] = a[r] + bcol;
    }
  }
}

// ---------------- sparse windowed attention: 4 (b,w,h) units per 256-thr block ----------------
__global__ __launch_bounds__(256) void attn_kernel(const bf16_t* __restrict__ qkv,
                                                   bf16_t* __restrict__ ctx) {
  __shared__ float Ks[4][20][64];
  __shared__ float Vs[4][20][64];
  int tid = threadIdx.x;
  int wid = tid >> 6, lane = tid & 63;
  int id = blockIdx.x * 4 + wid;     // ((b*128 + w)*12 + h)
  int h = id % 12;
  int bw = id / 12;
  int w = bw & 127, b = bw >> 7;
  const int hc = h * 64;

  { // window-token K/V rows 0..15
    int j = lane >> 2, dd = (lane & 3) * 16;
    size_t row = (size_t)b * 2560 + w * 16 + j;
    const bf16_t* kp = qkv + row * 2304 + 768 + hc + dd;
    bf16x8 k0 = *(const bf16x8*)kp;
    bf16x8 k1 = *(const bf16x8*)(kp + 8);
    bf16x8 u0 = *(const bf16x8*)(kp + 768);
    bf16x8 u1 = *(const bf16x8*)(kp + 776);
    #pragma unroll
    for (int i = 0; i < 8; i++) {
      Ks[wid][j][dd + i] = (float)k0[i]; Ks[wid][j][dd + 8 + i] = (float)k1[i];
      Vs[wid][j][dd + i] = (float)u0[i]; Vs[wid][j][dd + 8 + i] = (float)u1[i];
    }
  }
  if (lane < 16) { // carrier K/V rows 16..19
    int j = 16 + (lane >> 2), dd = (lane & 3) * 16;
    size_t row = (size_t)b * 2560 + 2048 + w * 4 + (lane >> 2);
    const bf16_t* kp = qkv + row * 2304 + 768 + hc + dd;
    bf16x8 k0 = *(const bf16x8*)kp;
    bf16x8 k1 = *(const bf16x8*)(kp + 8);
    bf16x8 u0 = *(const bf16x8*)(kp + 768);
    bf16x8 u1 = *(const bf16x8*)(kp + 776);
    #pragma unroll
    for (int i = 0; i < 8; i++) {
      Ks[wid][j][dd + i] = (float)k0[i]; Ks[wid][j][dd + 8 + i] = (float)k1[i];
      Vs[wid][j][dd + i] = (float)u0[i]; Vs[wid][j][dd + 8 + i] = (float)u1[i];
    }
  }
  // no barrier: all consumers are in the producing wave

  int qi = lane >> 2, c4 = lane & 3, d0 = c4 * 16;
  float qreg[16];
  {
    const bf16_t* qp = qkv + ((size_t)b * 2560 + w * 16 + qi) * 2304 + hc + d0;
    bf16x8 q0 = *(const bf16x8*)qp;
    bf16x8 q1 = *(const bf16x8*)(qp + 8);
    #pragma unroll
    for (int i = 0; i < 8; i++) { qreg[i] = (float)q0[i]; qreg[8 + i] = (float)q1[i]; }
  }

  float pl[5];
  #pragma unroll
  for (int j = 0; j < 20; j++) {
    float s = 0.f;
    #pragma unroll
    for (int i = 0; i < 16; i++) s += qreg[i] * Ks[wid][j][d0 + i];
    s += __shfl_xor(s, 1);
    s += __shfl_xor(s, 2);
    if ((j & 3) == c4) pl[j >> 2] = s;
  }
  float m = fmaxf(fmaxf(fmaxf(pl[0], pl[1]), fmaxf(pl[2], pl[3])), pl[4]);
  m = fmaxf(m, __shfl_xor(m, 1));
  m = fmaxf(m, __shfl_xor(m, 2));
  float sum = 0.f;
  #pragma unroll
  for (int i = 0; i < 5; i++) { pl[i] = __expf(pl[i] - m); sum += pl[i]; }
  sum += __shfl_xor(sum, 1);
  sum += __shfl_xor(sum, 2);
  float inv = 1.f / sum;

  float acc[16] = {};
  #pragma unroll
  for (int j = 0; j < 20; j++) {
    float pj = __shfl(pl[j >> 2], (qi << 2) | (j & 3));
    #pragma unroll
    for (int i = 0; i < 16; i++) acc[i] += pj * Vs[wid][j][d0 + i];
  }

  bf16_t* cp = ctx + ((size_t)(b * 2048 + w * 16 + qi)) * 768 + hc + d0;
  #pragma unroll
  for (int i = 0; i < 16; i++) cp[i] = (bf16_t)(acc[i] * inv);
}

// ---------------- gap-probe: trivial dispatch (measures dependent-dispatch latency) ----------------
__global__ __launch_bounds__(64) void nop_kernel(int* p) {
  if (threadIdx.x > 64) p[0] = 1;   // never true (blockDim=64); no memory traffic
}

// ---------------- launch ----------------
extern "C" void kernel_launch(void* const* d_in, const int* in_sizes, int n_in,
                              void* d_out, int out_size, void* d_ws, size_t ws_size,
                              hipStream_t stream) {
  (void)in_sizes; (void)n_in; (void)out_size; (void)ws_size;
  const float* x      = (const float*)d_in[0];
  const float* W_qkv  = (const float*)d_in[1];
  const float* b_qkv  = (const float*)d_in[2];
  const float* W_car  = (const float*)d_in[3];
  const float* b_car  = (const float*)d_in[4];
  const float* W_proj = (const float*)d_in[5];
  const float* b_proj = (const float*)d_in[6];
  const float* gamma  = (const float*)d_in[7];
  const float* beta   = (const float*)d_in[8];
  float* out = (float*)d_out;

  char* ws = (char*)d_ws;
  bf16_t* wt_qkv  = (bf16_t*)(ws + OFF_WT_QKV);
  bf16_t* wt_car  = (bf16_t*)(ws + OFF_WT_CAR);
  bf16_t* wt_proj = (bf16_t*)(ws + OFF_WT_PROJ);
  bf16_t* wmean   = (bf16_t*)(ws + OFF_WMEAN);
  float*  carP    = (float*) (ws + OFF_CARP);
  bf16_t* ln      = (bf16_t*)(ws + OFF_LN);
  bf16_t* qkv     = (bf16_t*)(ws + OFF_QKV);
  bf16_t* ctx     = (bf16_t*)(ws + OFF_CTX);
  int*    nopp    = (int*)   (ws + OFF_NOP);

  // 1. fused prep: weight transposes + window means
  prep_kernel<<<3136, 256, 0, stream>>>(W_qkv, W_car, W_proj, x,
                                        wt_qkv, wt_car, wt_proj, wmean);
  // 2. carrier GEMM, split-K=4 -> partials [4][256][768]
  gemm64_kernel<<<4 * 6 * 4, 256, 0, stream>>>(wmean, wt_car, carP, 4, 6, 192);
  // 3. LayerNorm(combined) -> bf16  (sums car partials + b_car inline)
  ln_kernel<<<5120, 256, 0, stream>>>(x, carP, b_car, gamma, beta, ln);
  // 4. QKV projection: 256^2 3-slot-ring pipelined GEMM -> plain [5120][2304] bf16
  gemm256_qkv<<<180, 512, 0, stream>>>(ln, wt_qkv, b_qkv, qkv);
  // 5. sparse windowed attention -> ctx bf16 (4 units per 256-thr block)
  attn_kernel<<<768, 256, 0, stream>>>(qkv, ctx);
  // 6. output projection -> d_out fp32 (128^2 tiles, 192 blocks)
  gemm128_proj<<<192, 256, 0, stream>>>(ctx, wt_proj, b_proj, out);
  // 7. DIAGNOSTIC: 10 sequential trivial dispatches -> dur delta = 10 x (gap + ~0.3us)
  for (int i = 0; i < 10; i++)
    nop_kernel<<<1, 64, 0, stream>>>(nopp);
}

// Round 10
// 72.662 us; speedup vs baseline: 1.3077x; 1.3077x over previous
//
#include <hip/hip_runtime.h>

typedef __bf16 bf16_t;
typedef __bf16 bf16x8 __attribute__((ext_vector_type(8)));
typedef float f32x4 __attribute__((ext_vector_type(4)));

#define GK 768   // inner K dim for every GEMM in this problem

// ---------------- workspace layout (bytes) ----------------
static constexpr size_t OFF_WT_QKV = 0;                                  // [2304][768] bf16
static constexpr size_t OFF_WT_CAR  = OFF_WT_QKV + (size_t)2304*768*2;   // [768][768] bf16
static constexpr size_t OFF_WT_PROJ = OFF_WT_CAR + (size_t)768*768*2;    // [768][768] bf16
static constexpr size_t OFF_WMEAN   = OFF_WT_PROJ + (size_t)768*768*2;   // [256][768] bf16
static constexpr size_t OFF_CARP    = OFF_WMEAN + (size_t)256*768*2;     // [4][256][768] f32 split-K partials
static constexpr size_t OFF_LN      = OFF_CARP + (size_t)4*256*768*4;    // [5120][768] bf16
static constexpr size_t OFF_QKV     = OFF_LN + (size_t)5120*768*2;       // [5120][2304] bf16 (q|k|v)
static constexpr size_t OFF_CTX     = OFF_QKV + (size_t)5120*2304*2;     // [2][2048][768] bf16

// ---------------- async global->LDS (16B per lane) ----------------
__device__ __forceinline__ void gload16(const bf16_t* g, bf16_t* lds_wave_base) {
  __builtin_amdgcn_global_load_lds(
      (const __attribute__((address_space(1))) unsigned int*)g,
      (__attribute__((address_space(3))) unsigned int*)lds_wave_base,
      16, 0, 0);
}

// ---------------- transpose helper (shared by prep/carplus) ----------------
__device__ __forceinline__ void do_transpose(const float* __restrict__ W,
                                             bf16_t* __restrict__ Wt,
                                             int Ndim, int kb, int nb,
                                             float (*tile)[33]) {
  int tx = threadIdx.x & 31, ty = threadIdx.x >> 5;   // ty in 0..7
  #pragma unroll
  for (int i = 0; i < 32; i += 8)
    tile[ty + i][tx] = W[(size_t)(kb + ty + i) * Ndim + nb + tx];
  __syncthreads();
  #pragma unroll
  for (int i = 0; i < 32; i += 8)
    Wt[(size_t)(nb + ty + i) * GK + kb + tx] = (bf16_t)tile[tx][ty + i];
}

// ---------------- step 1: wt_car transpose + window means (only what car needs) ----------------
__global__ __launch_bounds__(256) void prep_small(const float* __restrict__ W_car,
                                                  const float* __restrict__ x,
                                                  bf16_t* __restrict__ wt_car,
                                                  bf16_t* __restrict__ wm) {
  __shared__ float tile[32][33];
  int bid = blockIdx.x;
  if (bid < 576) {
    do_transpose(W_car, wt_car, 768, (bid % 24) * 32, (bid / 24) * 32, tile);
  } else {
    int w = bid - 576;             // 0..255  (b*128 + window)
    int b = w >> 7, ww = w & 127;
    const float* base = x + ((size_t)b * 2048 + (size_t)ww * 16) * 768;
    for (int d = threadIdx.x; d < 768; d += 256) {
      float s = 0.f;
      #pragma unroll
      for (int i = 0; i < 16; i++) s += base[(size_t)i * 768 + d];
      wm[(size_t)w * 768 + d] = (bf16_t)(s * (1.f / 16.f));
    }
  }
}

// ---------------- step 2: carrier GEMM (96 blocks) + qkv/proj transposes as concurrent filler ----------------
__global__ __launch_bounds__(256) void car_plus(const bf16_t* __restrict__ wmean,
                                                const bf16_t* __restrict__ wt_car,
                                                float* __restrict__ carP,
                                                const float* __restrict__ W_qkv,
                                                const float* __restrict__ W_proj,
                                                bf16_t* __restrict__ wt_qkv,
                                                bf16_t* __restrict__ wt_proj) {
  __shared__ float tile[32][33];
  __shared__ __align__(16) bf16_t As[64 * 32];
  __shared__ __align__(16) bf16_t Bs[128 * 32];
  int bid = blockIdx.x;

  if (bid >= 96) {   // transpose filler blocks
    if (bid < 1824) { int q = bid - 96;   do_transpose(W_qkv,  wt_qkv,  2304, (q % 24) * 32, (q / 24) * 32, tile); }
    else            { int q = bid - 1824; do_transpose(W_proj, wt_proj, 768,  (q % 24) * 32, (q / 24) * 32, tile); }
    return;
  }

  // carrier GEMM: 64x128 tiles, split-K=4 -> carP[kz][256][768]
  int bm = bid % 4;
  int rest = bid / 4;
  int bn = rest % 6;
  int kz = rest / 6;
  int t = threadIdx.x, wid = t >> 6, lane = t & 63;
  int wm = wid >> 1, wn = wid & 1;
  int sr = t >> 2, sk = (t & 3) * 8;
  const bf16_t* gA = wmean + (size_t)(bm * 64 + sr) * GK + sk;
  const bf16_t* gB = wt_car + (size_t)(bn * 128 + sr) * GK + sk;
  bf16_t* lA  = As + wid * 512;
  bf16_t* lB0 = Bs + wid * 512;
  bf16_t* lB1 = Bs + 2048 + wid * 512;
  int fr = lane & 15, fk = (lane >> 4) * 8;

  f32x4 acc[2][4] = {};
  int k0 = kz * 192, kend = k0 + 192;
  for (; k0 < kend; k0 += 32) {
    gload16(gA + k0,           lA);
    gload16(gB + k0,           lB0);
    gload16(gB + k0 + 64 * GK, lB1);
    __syncthreads();
    bf16x8 af[2], bfr[4];
    #pragma unroll
    for (int i = 0; i < 2; i++)
      af[i] = *(const bf16x8*)(As + (wm * 32 + i * 16 + fr) * 32 + fk);
    #pragma unroll
    for (int j = 0; j < 4; j++)
      bfr[j] = *(const bf16x8*)(Bs + (wn * 64 + j * 16 + fr) * 32 + fk);
    #pragma unroll
    for (int i = 0; i < 2; i++)
      #pragma unroll
      for (int j = 0; j < 4; j++)
        acc[i][j] = __builtin_amdgcn_mfma_f32_16x16x32_bf16(af[i], bfr[j], acc[i][j], 0, 0, 0);
    __syncthreads();
  }

  #pragma unroll
  for (int i = 0; i < 2; i++) {
    int rbase = bm * 64 + wm * 32 + i * 16 + ((lane >> 4) << 2);
    #pragma unroll
    for (int j = 0; j < 4; j++) {
      int col = bn * 128 + wn * 64 + j * 16 + (lane & 15);
      f32x4 a = acc[i][j];
      #pragma unroll
      for (int r = 0; r < 4; r++)
        carP[(size_t)kz * 196608 + (size_t)(rbase + r) * 768 + col] = a[r];
    }
  }
}

// ---------------- fused LayerNorm over "combined" rows -> bf16 ----------------
__global__ __launch_bounds__(256) void ln_kernel(const float* __restrict__ x,
                                                 const float* __restrict__ carP,
                                                 const float* __restrict__ b_car,
                                                 const float* __restrict__ gamma,
                                                 const float* __restrict__ beta,
                                                 bf16_t* __restrict__ out) {
  __shared__ float red[8];
  int row = blockIdx.x;                 // 0 .. 5119
  int b = row / 2560, n = row - b * 2560;
  int t = threadIdx.x;
  float v0, v1, v2;
  if (n < 2048) {
    const float* src = x + ((size_t)b * 2048 + n) * 768;
    v0 = src[t]; v1 = src[t + 256]; v2 = src[t + 512];
  } else {
    size_t ci = (size_t)(b * 128 + ((n - 2048) >> 2)) * 768;
    const float* p0 = carP + ci;
    const float* p1 = carP + ci + 196608;
    const float* p2 = carP + ci + 2 * 196608;
    const float* p3 = carP + ci + 3 * 196608;
    v0 = p0[t]       + p1[t]       + p2[t]       + p3[t]       + b_car[t];
    v1 = p0[t + 256] + p1[t + 256] + p2[t + 256] + p3[t + 256] + b_car[t + 256];
    v2 = p0[t + 512] + p1[t + 512] + p2[t + 512] + p3[t + 512] + b_car[t + 512];
  }
  float s = v0 + v1 + v2;
  float q = v0 * v0 + v1 * v1 + v2 * v2;
  #pragma unroll
  for (int o = 32; o > 0; o >>= 1) { s += __shfl_down(s, o); q += __shfl_down(q, o); }
  int wv = t >> 6;
  if ((t & 63) == 0) { red[wv] = s; red[4 + wv] = q; }
  __syncthreads();
  s = red[0] + red[1] + red[2] + red[3];
  q = red[4] + red[5] + red[6] + red[7];
  float mean = s * (1.f / 768.f);
  float var  = q * (1.f / 768.f) - mean * mean;
  float rstd = rsqrtf(var + 1e-5f);
  bf16_t* o0 = out + (size_t)row * 768;
  o0[t]       = (bf16_t)((v0 - mean) * rstd * gamma[t]       + beta[t]);
  o0[t + 256] = (bf16_t)((v1 - mean) * rstd * gamma[t + 256] + beta[t + 256]);
  o0[t + 512] = (bf16_t)((v2 - mean) * rstd * gamma[t + 512] + beta[t + 512]);
}

// ---------------- QKV GEMM: 256x256 tile, BK=32, 3-slot ring, counted vmcnt (R7, verified) ----------------
__global__ __launch_bounds__(512, 1) void gemm256_qkv(const bf16_t* __restrict__ A,
                                                      const bf16_t* __restrict__ Bt,
                                                      const float* __restrict__ bias,
                                                      bf16_t* __restrict__ qkv) {
  __shared__ __align__(16) bf16_t smem[3][2][8192];   // [slot][A=0/B=1][r*32 + swz]

  // bijective XCD swizzle (m204): nwg=180, xcd 0..3 get 23 blocks, 4..7 get 22
  int xcd = blockIdx.x & 7, idx = blockIdx.x >> 3;
  int wgid = (xcd < 4 ? xcd * 23 : 92 + (xcd - 4) * 22) + idx;
  int bm = wgid / 9, bn = wgid % 9;

  int t = threadIdx.x;
  int w = t >> 6, lane = t & 63;
  int wm = w >> 2, wn = w & 3;          // wm: 128-row band, wn: 64-col band
  int fr = lane & 15, s16 = lane >> 4;

  const bf16_t* Ab = A  + (size_t)bm * 256 * GK;
  const bf16_t* Bb = Bt + (size_t)bn * 256 * GK;

  const int srow  = t >> 2;                              // 0..127
  const int skoff = (((t & 3) ^ ((t >> 3) & 3)) << 3);   // inverse-swizzled k-elem offset
  const int wbase = w * 512;                             // wave-uniform dest (HW adds lane*16B)

  auto stageT = [&](const bf16_t* src, int mat, int T, int s) {
    const bf16_t* g = src + (size_t)srow * GK + T * 32 + skoff;
    gload16(g,            &smem[s][mat][wbase]);
    gload16(g + 128 * GK, &smem[s][mat][4096 + wbase]);
  };
  auto rdA = [&](int s, int m) -> bf16x8 {
    int r = wm * 128 + m * 16 + fr;
    return *(const bf16x8*)(&smem[s][0][r * 32 + ((s16 ^ ((r >> 1) & 3)) << 3)]);
  };
  auto rdB = [&](int s, int n) -> bf16x8 {
    int r = wn * 64 + n * 16 + fr;
    return *(const bf16x8*)(&smem[s][1][r * 32 + ((s16 ^ ((r >> 1) & 3)) << 3)]);
  };

  f32x4 acc[8][4] = {};

  // prologue: tile 0 -> slot 0, tile 1 -> slot 1 (each wave: 8 loads)
  stageT(Ab, 0, 0, 0); stageT(Bb, 1, 0, 0);
  stageT(Ab, 0, 1, 1); stageT(Bb, 1, 1, 1);
  asm volatile("s_waitcnt vmcnt(4)" ::: "memory");   // tile 0 landed; tile 1's 4 in flight
  __builtin_amdgcn_s_barrier();

  int s = 0, s2 = 2;
  #pragma unroll 3
  for (int T = 0; T < 24; ++T) {
    const bool pf = (T <= 21);
    bf16x8 bfr[4], a0[4], a1[4];
    { // ---- q0: read B n0-3 + A m0-3; stage A(T+2); MFMA m0-3 ----
      #pragma unroll
      for (int n = 0; n < 4; n++) bfr[n] = rdB(s, n);
      #pragma unroll
      for (int m = 0; m < 4; m++) a0[m] = rdA(s, m);
      if (pf) stageT(Ab, 0, T + 2, s2);
      __builtin_amdgcn_s_setprio(1);
      #pragma unroll
      for (int m = 0; m < 4; m++)
        #pragma unroll
        for (int n = 0; n < 4; n++)
          acc[m][n] = __builtin_amdgcn_mfma_f32_16x16x32_bf16(a0[m], bfr[n], acc[m][n], 0, 0, 0);
      __builtin_amdgcn_s_setprio(0);
      __builtin_amdgcn_s_barrier();
    }
    { // ---- q1: read A m4-7; stage B(T+2); MFMA m4-7; tile-boundary wait ----
      #pragma unroll
      for (int m = 0; m < 4; m++) a1[m] = rdA(s, 4 + m);
      if (pf) stageT(Bb, 1, T + 2, s2);
      __builtin_amdgcn_s_setprio(1);
      #pragma unroll
      for (int m = 0; m < 4; m++)
        #pragma unroll
        for (int n = 0; n < 4; n++)
          acc[4 + m][n] = __builtin_amdgcn_mfma_f32_16x16x32_bf16(a1[m], bfr[n], acc[4 + m][n], 0, 0, 0);
      __builtin_amdgcn_s_setprio(0);
      if (pf)            asm volatile("s_waitcnt vmcnt(4)" ::: "memory");  // T+1 landed, T+2 in flight
      else if (T == 22)  asm volatile("s_waitcnt vmcnt(0)" ::: "memory");  // drain for last tile
      __builtin_amdgcn_s_barrier();
    }
    s  = (s  == 2) ? 0 : s  + 1;
    s2 = (s2 == 2) ? 0 : s2 + 1;
  }

  // epilogue: D layout col = lane&15, row = (lane>>4)*4 + reg; plain row-major store
  #pragma unroll
  for (int m = 0; m < 8; m++) {
    int rbase = bm * 256 + wm * 128 + m * 16 + (s16 << 2);
    #pragma unroll
    for (int n = 0; n < 4; n++) {
      int col = bn * 256 + wn * 64 + n * 16 + fr;
      float bcol = bias[col];
      float sc = (col < 768) ? 0.125f : 1.f;   // fold SCALE into q section
      f32x4 a = acc[m][n];
      #pragma unroll
      for (int r2 = 0; r2 < 4; r2++)
        qkv[(size_t)(rbase + r2) * 2304 + col] = (bf16_t)((a[r2] + bcol) * sc);
    }
  }
}

// ---------------- sparse windowed attention: 4 (b,w,h) units per 256-thr block ----------------
__global__ __launch_bounds__(256) void attn_kernel(const bf16_t* __restrict__ qkv,
                                                   bf16_t* __restrict__ ctx) {
  __shared__ float Ks[4][20][64];
  __shared__ float Vs[4][20][64];
  int tid = threadIdx.x;
  int wid = tid >> 6, lane = tid & 63;
  int id = blockIdx.x * 4 + wid;     // ((b*128 + w)*12 + h)
  int h = id % 12;
  int bw = id / 12;
  int w = bw & 127, b = bw >> 7;
  const int hc = h * 64;

  { // window-token K/V rows 0..15
    int j = lane >> 2, dd = (lane & 3) * 16;
    size_t row = (size_t)b * 2560 + w * 16 + j;
    const bf16_t* kp = qkv + row * 2304 + 768 + hc + dd;
    bf16x8 k0 = *(const bf16x8*)kp;
    bf16x8 k1 = *(const bf16x8*)(kp + 8);
    bf16x8 u0 = *(const bf16x8*)(kp + 768);
    bf16x8 u1 = *(const bf16x8*)(kp + 776);
    #pragma unroll
    for (int i = 0; i < 8; i++) {
      Ks[wid][j][dd + i] = (float)k0[i]; Ks[wid][j][dd + 8 + i] = (float)k1[i];
      Vs[wid][j][dd + i] = (float)u0[i]; Vs[wid][j][dd + 8 + i] = (float)u1[i];
    }
  }
  if (lane < 16) { // carrier K/V rows 16..19
    int j = 16 + (lane >> 2), dd = (lane & 3) * 16;
    size_t row = (size_t)b * 2560 + 2048 + w * 4 + (lane >> 2);
    const bf16_t* kp = qkv + row * 2304 + 768 + hc + dd;
    bf16x8 k0 = *(const bf16x8*)kp;
    bf16x8 k1 = *(const bf16x8*)(kp + 8);
    bf16x8 u0 = *(const bf16x8*)(kp + 768);
    bf16x8 u1 = *(const bf16x8*)(kp + 776);
    #pragma unroll
    for (int i = 0; i < 8; i++) {
      Ks[wid][j][dd + i] = (float)k0[i]; Ks[wid][j][dd + 8 + i] = (float)k1[i];
      Vs[wid][j][dd + i] = (float)u0[i]; Vs[wid][j][dd + 8 + i] = (float)u1[i];
    }
  }
  // no barrier: all consumers are in the producing wave

  int qi = lane >> 2, c4 = lane & 3, d0 = c4 * 16;
  float qreg[16];
  {
    const bf16_t* qp = qkv + ((size_t)b * 2560 + w * 16 + qi) * 2304 + hc + d0;
    bf16x8 q0 = *(const bf16x8*)qp;
    bf16x8 q1 = *(const bf16x8*)(qp + 8);
    #pragma unroll
    for (int i = 0; i < 8; i++) { qreg[i] = (float)q0[i]; qreg[8 + i] = (float)q1[i]; }
  }

  float pl[5];
  #pragma unroll
  for (int j = 0; j < 20; j++) {
    float s = 0.f;
    #pragma unroll
    for (int i = 0; i < 16; i++) s += qreg[i] * Ks[wid][j][d0 + i];
    s += __shfl_xor(s, 1);
    s += __shfl_xor(s, 2);
    if ((j & 3) == c4) pl[j >> 2] = s;
  }
  float m = fmaxf(fmaxf(fmaxf(pl[0], pl[1]), fmaxf(pl[2], pl[3])), pl[4]);
  m = fmaxf(m, __shfl_xor(m, 1));
  m = fmaxf(m, __shfl_xor(m, 2));
  float sum = 0.f;
  #pragma unroll
  for (int i = 0; i < 5; i++) { pl[i] = __expf(pl[i] - m); sum += pl[i]; }
  sum += __shfl_xor(sum, 1);
  sum += __shfl_xor(sum, 2);
  float inv = 1.f / sum;

  float acc[16] = {};
  #pragma unroll
  for (int j = 0; j < 20; j++) {
    float pj = __shfl(pl[j >> 2], (qi << 2) | (j & 3));
    #pragma unroll
    for (int i = 0; i < 16; i++) acc[i] += pj * Vs[wid][j][d0 + i];
  }

  bf16_t* cp = ctx + ((size_t)(b * 2048 + w * 16 + qi)) * 768 + hc + d0;
  #pragma unroll
  for (int i = 0; i < 16; i++) cp[i] = (bf16_t)(acc[i] * inv);
}

// ---------------- proj GEMM: 128x128 tile, BK=32, 3-slot ring, counted vmcnt (R7 schedule port) ----------------
// 256 thr = 4 waves (2M x 2N); per-wave out 64x64 (acc[4][4]); 24 K-tiles.
// LDS: 3 slots x {A,B} x [128][32] bf16 = 48KB. Same swizzle algebra as gemm256 ([*][32] subtile,
// chunk ^= (r>>1)&3; skoff identity holds for both 64-row lines since 64 is 0 mod 8).
__global__ __launch_bounds__(256, 1) void gemm128_proj(const bf16_t* __restrict__ A,
                                                       const bf16_t* __restrict__ Bt,
                                                       const float* __restrict__ bias,
                                                       float* __restrict__ outF) {
  __shared__ __align__(16) bf16_t smem[3][2][4096];   // [slot][A=0/B=1][r*32 + swz]

  int bm = blockIdx.x % 32;           // M = 4096 -> 32 tiles
  int bn = blockIdx.x / 32;           // N = 768  -> 6 tiles
  int t = threadIdx.x;
  int w = t >> 6, lane = t & 63;
  int wm = w >> 1, wn = w & 1;        // 2x2 waves, per-wave 64x64
  int fr = lane & 15, s16 = lane >> 4;

  const bf16_t* Ab = A  + (size_t)bm * 128 * GK;
  const bf16_t* Bb = Bt + (size_t)bn * 128 * GK;

  const int srow  = t >> 2;                              // 0..63
  const int skoff = (((t & 3) ^ ((t >> 3) & 3)) << 3);
  const int wbase = w * 512;                             // 4 waves x 512 bf16 = one 4KB line

  auto stageT = [&](const bf16_t* src, int mat, int T, int s) {
    const bf16_t* g = src + (size_t)srow * GK + T * 32 + skoff;
    gload16(g,           &smem[s][mat][wbase]);
    gload16(g + 64 * GK, &smem[s][mat][2048 + wbase]);
  };
  auto rdA = [&](int s, int m) -> bf16x8 {
    int r = wm * 64 + m * 16 + fr;
    return *(const bf16x8*)(&smem[s][0][r * 32 + ((s16 ^ ((r >> 1) & 3)) << 3)]);
  };
  auto rdB = [&](int s, int n) -> bf16x8 {
    int r = wn * 64 + n * 16 + fr;
    return *(const bf16x8*)(&smem[s][1][r * 32 + ((s16 ^ ((r >> 1) & 3)) << 3)]);
  };

  f32x4 acc[4][4] = {};

  stageT(Ab, 0, 0, 0); stageT(Bb, 1, 0, 0);
  stageT(Ab, 0, 1, 1); stageT(Bb, 1, 1, 1);
  asm volatile("s_waitcnt vmcnt(4)" ::: "memory");
  __builtin_amdgcn_s_barrier();

  int s = 0, s2 = 2;
  #pragma unroll 3
  for (int T = 0; T < 24; ++T) {
    const bool pf = (T <= 21);
    bf16x8 bfr[4], af[4];
    #pragma unroll
    for (int n = 0; n < 4; n++) bfr[n] = rdB(s, n);
    #pragma unroll
    for (int m = 0; m < 4; m++) af[m] = rdA(s, m);
    if (pf) { stageT(Ab, 0, T + 2, s2); stageT(Bb, 1, T + 2, s2); }
    __builtin_amdgcn_s_setprio(1);
    #pragma unroll
    for (int m = 0; m < 4; m++)
      #pragma unroll
      for (int n = 0; n < 4; n++)
        acc[m][n] = __builtin_amdgcn_mfma_f32_16x16x32_bf16(af[m], bfr[n], acc[m][n], 0, 0, 0);
    __builtin_amdgcn_s_setprio(0);
    if (pf)            asm volatile("s_waitcnt vmcnt(4)" ::: "memory");  // T+1 landed, T+2 in flight
    else if (T == 22)  asm volatile("s_waitcnt vmcnt(0)" ::: "memory");
    __builtin_amdgcn_s_barrier();
    s  = (s  == 2) ? 0 : s  + 1;
    s2 = (s2 == 2) ? 0 : s2 + 1;
  }

  #pragma unroll
  for (int m = 0; m < 4; m++) {
    int rbase = bm * 128 + wm * 64 + m * 16 + (s16 << 2);
    #pragma unroll
    for (int n = 0; n < 4; n++) {
      int col = bn * 128 + wn * 64 + n * 16 + fr;
      float bcol = bias[col];
      f32x4 a = acc[m][n];
      #pragma unroll
      for (int r = 0; r < 4; r++)
        outF[(size_t)(rbase + r) * 768 + col] = a[r] + bcol;
    }
  }
}

// ---------------- launch ----------------
extern "C" void kernel_launch(void* const* d_in, const int* in_sizes, int n_in,
                              void* d_out, int out_size, void* d_ws, size_t ws_size,
                              hipStream_t stream) {
  (void)in_sizes; (void)n_in; (void)out_size; (void)ws_size;
  const float* x      = (const float*)d_in[0];
  const float* W_qkv  = (const float*)d_in[1];
  const float* b_qkv  = (const float*)d_in[2];
  const float* W_car  = (const float*)d_in[3];
  const float* b_car  = (const float*)d_in[4];
  const float* W_proj = (const float*)d_in[5];
  const float* b_proj = (const float*)d_in[6];
  const float* gamma  = (const float*)d_in[7];
  const float* beta   = (const float*)d_in[8];
  float* out = (float*)d_out;

  char* ws = (char*)d_ws;
  bf16_t* wt_qkv  = (bf16_t*)(ws + OFF_WT_QKV);
  bf16_t* wt_car  = (bf16_t*)(ws + OFF_WT_CAR);
  bf16_t* wt_proj = (bf16_t*)(ws + OFF_WT_PROJ);
  bf16_t* wmean   = (bf16_t*)(ws + OFF_WMEAN);
  float*  carP    = (float*) (ws + OFF_CARP);
  bf16_t* ln      = (bf16_t*)(ws + OFF_LN);
  bf16_t* qkv     = (bf16_t*)(ws + OFF_QKV);
  bf16_t* ctx     = (bf16_t*)(ws + OFF_CTX);

  // 1. minimal prep for car: wt_car transpose + window means
  prep_small<<<832, 256, 0, stream>>>(W_car, x, wt_car, wmean);
  // 2. carrier GEMM (96 blocks) + wt_qkv/wt_proj transposes running concurrently
  car_plus<<<2400, 256, 0, stream>>>(wmean, wt_car, carP, W_qkv, W_proj, wt_qkv, wt_proj);
  // 3. LayerNorm(combined) -> bf16  (sums car partials + b_car inline)
  ln_kernel<<<5120, 256, 0, stream>>>(x, carP, b_car, gamma, beta, ln);
  // 4. QKV projection: 256^2 3-slot-ring pipelined GEMM -> plain [5120][2304] bf16
  gemm256_qkv<<<180, 512, 0, stream>>>(ln, wt_qkv, b_qkv, qkv);
  // 5. sparse windowed attention -> ctx bf16 (4 units per 256-thr block)
  attn_kernel<<<768, 256, 0, stream>>>(qkv, ctx);
  // 6. output projection: 128^2 3-slot-ring pipelined GEMM -> d_out fp32
  gemm128_proj<<<192, 256, 0, stream>>>(ctx, wt_proj, b_proj, out);
}

// Round 11
// 72.525 us; speedup vs baseline: 1.3102x; 1.0019x over previous
//
#include <hip/hip_runtime.h>

typedef __bf16 bf16_t;
typedef __bf16 bf16x8 __attribute__((ext_vector_type(8)));
typedef __bf16 bf16x4 __attribute__((ext_vector_type(4)));
typedef float f32x4 __attribute__((ext_vector_type(4)));

#define GK 768   // inner K dim for every GEMM in this problem

// ---------------- workspace layout (bytes) ----------------
static constexpr size_t OFF_WT_QKV = 0;                                  // [2304][768] bf16
static constexpr size_t OFF_WT_CAR  = OFF_WT_QKV + (size_t)2304*768*2;   // [768][768] bf16
static constexpr size_t OFF_WT_PROJ = OFF_WT_CAR + (size_t)768*768*2;    // [768][768] bf16
static constexpr size_t OFF_WMEAN   = OFF_WT_PROJ + (size_t)768*768*2;   // [256][768] bf16
static constexpr size_t OFF_CARP    = OFF_WMEAN + (size_t)256*768*2;     // [4][256][768] f32 split-K partials
static constexpr size_t OFF_LN      = OFF_CARP + (size_t)4*256*768*4;    // [5120][768] bf16
static constexpr size_t OFF_QKV     = OFF_LN + (size_t)5120*768*2;       // [5120][2304] bf16 (q|k|v)
static constexpr size_t OFF_CTX     = OFF_QKV + (size_t)5120*2304*2;     // [2][2048][768] bf16

// ---------------- async global->LDS (16B per lane) ----------------
__device__ __forceinline__ void gload16(const bf16_t* g, bf16_t* lds_wave_base) {
  __builtin_amdgcn_global_load_lds(
      (const __attribute__((address_space(1))) unsigned int*)g,
      (__attribute__((address_space(3))) unsigned int*)lds_wave_base,
      16, 0, 0);
}

// ---------------- transpose helper: scalar coalesced fp32 loads, VECTORIZED bf16x4 stores ----------------
__device__ __forceinline__ void do_transpose(const float* __restrict__ W,
                                             bf16_t* __restrict__ Wt,
                                             int Ndim, int kb, int nb,
                                             float (*tile)[33]) {
  int tx = threadIdx.x & 31, ty = threadIdx.x >> 5;   // ty in 0..7
  #pragma unroll
  for (int i = 0; i < 32; i += 8)
    tile[ty + i][tx] = W[(size_t)(kb + ty + i) * Ndim + nb + tx];
  __syncthreads();
  // write phase: thread -> (n-row nr = t>>3, k-quad k4 = t&7); one bf16x4 store (512B/wave-instr)
  int k4 = threadIdx.x & 7, nr = threadIdx.x >> 3;
  bf16x4 o;
  o[0] = (bf16_t)tile[k4 * 4 + 0][nr];
  o[1] = (bf16_t)tile[k4 * 4 + 1][nr];
  o[2] = (bf16_t)tile[k4 * 4 + 2][nr];
  o[3] = (bf16_t)tile[k4 * 4 + 3][nr];
  *(bf16x4*)(&Wt[(size_t)(nb + nr) * GK + kb + k4 * 4]) = o;
}

// ---------------- step 1: wt_car transpose + window means (float4/bf16x4 vectorized) ----------------
__global__ __launch_bounds__(256) void prep_small(const float* __restrict__ W_car,
                                                  const float* __restrict__ x,
                                                  bf16_t* __restrict__ wt_car,
                                                  bf16_t* __restrict__ wm) {
  __shared__ float tile[32][33];
  int bid = blockIdx.x;
  if (bid < 576) {
    do_transpose(W_car, wt_car, 768, (bid % 24) * 32, (bid / 24) * 32, tile);
  } else {
    int w = bid - 576;             // 0..255  (b*128 + window)
    if (threadIdx.x < 192) {
      int b = w >> 7, ww = w & 127;
      const float* base = x + ((size_t)b * 2048 + (size_t)ww * 16) * 768;
      int d4 = threadIdx.x * 4;
      float sx = 0.f, sy = 0.f, sz = 0.f, sw = 0.f;
      #pragma unroll
      for (int i = 0; i < 16; i++) {
        float4 u = *(const float4*)(base + (size_t)i * 768 + d4);
        sx += u.x; sy += u.y; sz += u.z; sw += u.w;
      }
      bf16x4 o;
      o[0] = (bf16_t)(sx * (1.f / 16.f));
      o[1] = (bf16_t)(sy * (1.f / 16.f));
      o[2] = (bf16_t)(sz * (1.f / 16.f));
      o[3] = (bf16_t)(sw * (1.f / 16.f));
      *(bf16x4*)(&wm[(size_t)w * 768 + d4]) = o;
    }
  }
}

// ---------------- step 2: carrier GEMM (96 blocks) + qkv/proj transposes as concurrent filler ----------------
__global__ __launch_bounds__(256) void car_plus(const bf16_t* __restrict__ wmean,
                                                const bf16_t* __restrict__ wt_car,
                                                float* __restrict__ carP,
                                                const float* __restrict__ W_qkv,
                                                const float* __restrict__ W_proj,
                                                bf16_t* __restrict__ wt_qkv,
                                                bf16_t* __restrict__ wt_proj) {
  __shared__ float tile[32][33];
  __shared__ __align__(16) bf16_t As[64 * 32];
  __shared__ __align__(16) bf16_t Bs[128 * 32];
  int bid = blockIdx.x;

  if (bid >= 96) {   // transpose filler blocks
    if (bid < 1824) { int q = bid - 96;   do_transpose(W_qkv,  wt_qkv,  2304, (q % 24) * 32, (q / 24) * 32, tile); }
    else            { int q = bid - 1824; do_transpose(W_proj, wt_proj, 768,  (q % 24) * 32, (q / 24) * 32, tile); }
    return;
  }

  // carrier GEMM: 64x128 tiles, split-K=4 -> carP[kz][256][768]
  int bm = bid % 4;
  int rest = bid / 4;
  int bn = rest % 6;
  int kz = rest / 6;
  int t = threadIdx.x, wid = t >> 6, lane = t & 63;
  int wm = wid >> 1, wn = wid & 1;
  int sr = t >> 2, sk = (t & 3) * 8;
  const bf16_t* gA = wmean + (size_t)(bm * 64 + sr) * GK + sk;
  const bf16_t* gB = wt_car + (size_t)(bn * 128 + sr) * GK + sk;
  bf16_t* lA  = As + wid * 512;
  bf16_t* lB0 = Bs + wid * 512;
  bf16_t* lB1 = Bs + 2048 + wid * 512;
  int fr = lane & 15, fk = (lane >> 4) * 8;

  f32x4 acc[2][4] = {};
  int k0 = kz * 192, kend = k0 + 192;
  for (; k0 < kend; k0 += 32) {
    gload16(gA + k0,           lA);
    gload16(gB + k0,           lB0);
    gload16(gB + k0 + 64 * GK, lB1);
    __syncthreads();
    bf16x8 af[2], bfr[4];
    #pragma unroll
    for (int i = 0; i < 2; i++)
      af[i] = *(const bf16x8*)(As + (wm * 32 + i * 16 + fr) * 32 + fk);
    #pragma unroll
    for (int j = 0; j < 4; j++)
      bfr[j] = *(const bf16x8*)(Bs + (wn * 64 + j * 16 + fr) * 32 + fk);
    #pragma unroll
    for (int i = 0; i < 2; i++)
      #pragma unroll
      for (int j = 0; j < 4; j++)
        acc[i][j] = __builtin_amdgcn_mfma_f32_16x16x32_bf16(af[i], bfr[j], acc[i][j], 0, 0, 0);
    __syncthreads();
  }

  #pragma unroll
  for (int i = 0; i < 2; i++) {
    int rbase = bm * 64 + wm * 32 + i * 16 + ((lane >> 4) << 2);
    #pragma unroll
    for (int j = 0; j < 4; j++) {
      int col = bn * 128 + wn * 64 + j * 16 + (lane & 15);
      f32x4 a = acc[i][j];
      #pragma unroll
      for (int r = 0; r < 4; r++)
        carP[(size_t)kz * 196608 + (size_t)(rbase + r) * 768 + col] = a[r];
    }
  }
}

// ---------------- fused LayerNorm -> bf16 (float4 loads, bf16x4 stores, 192 thr) ----------------
__global__ __launch_bounds__(192) void ln_kernel(const float* __restrict__ x,
                                                 const float* __restrict__ carP,
                                                 const float* __restrict__ b_car,
                                                 const float* __restrict__ gamma,
                                                 const float* __restrict__ beta,
                                                 bf16_t* __restrict__ out) {
  __shared__ float red[6];
  int row = blockIdx.x;                 // 0 .. 5119
  int b = row / 2560, n = row - b * 2560;
  int t = threadIdx.x;                  // 0..191, covers 768 floats as float4
  float4 v;
  if (n < 2048) {
    v = *(const float4*)(x + ((size_t)b * 2048 + n) * 768 + t * 4);
  } else {
    size_t ci = (size_t)(b * 128 + ((n - 2048) >> 2)) * 768 + t * 4;
    float4 a0 = *(const float4*)(carP + ci);
    float4 a1 = *(const float4*)(carP + ci + 196608);
    float4 a2 = *(const float4*)(carP + ci + 2 * 196608);
    float4 a3 = *(const float4*)(carP + ci + 3 * 196608);
    float4 bc = *(const float4*)(b_car + t * 4);
    v.x = a0.x + a1.x + a2.x + a3.x + bc.x;
    v.y = a0.y + a1.y + a2.y + a3.y + bc.y;
    v.z = a0.z + a1.z + a2.z + a3.z + bc.z;
    v.w = a0.w + a1.w + a2.w + a3.w + bc.w;
  }
  float s = v.x + v.y + v.z + v.w;
  float q = v.x * v.x + v.y * v.y + v.z * v.z + v.w * v.w;
  #pragma unroll
  for (int o = 32; o > 0; o >>= 1) { s += __shfl_down(s, o); q += __shfl_down(q, o); }
  int wv = t >> 6;
  if ((t & 63) == 0) { red[wv] = s; red[3 + wv] = q; }
  __syncthreads();
  s = red[0] + red[1] + red[2];
  q = red[3] + red[4] + red[5];
  float mean = s * (1.f / 768.f);
  float var  = q * (1.f / 768.f) - mean * mean;
  float rstd = rsqrtf(var + 1e-5f);
  float4 g4 = *(const float4*)(gamma + t * 4);
  float4 be4 = *(const float4*)(beta + t * 4);
  bf16x4 o4;
  o4[0] = (bf16_t)((v.x - mean) * rstd * g4.x + be4.x);
  o4[1] = (bf16_t)((v.y - mean) * rstd * g4.y + be4.y);
  o4[2] = (bf16_t)((v.z - mean) * rstd * g4.z + be4.z);
  o4[3] = (bf16_t)((v.w - mean) * rstd * g4.w + be4.w);
  *(bf16x4*)(out + (size_t)row * 768 + t * 4) = o4;
}

// ---------------- QKV GEMM: 256x256 tile, BK=32, 3-slot ring, counted vmcnt (R7, verified) ----------------
__global__ __launch_bounds__(512, 1) void gemm256_qkv(const bf16_t* __restrict__ A,
                                                      const bf16_t* __restrict__ Bt,
                                                      const float* __restrict__ bias,
                                                      bf16_t* __restrict__ qkv) {
  __shared__ __align__(16) bf16_t smem[3][2][8192];   // [slot][A=0/B=1][r*32 + swz]

  // bijective XCD swizzle (m204): nwg=180, xcd 0..3 get 23 blocks, 4..7 get 22
  int xcd = blockIdx.x & 7, idx = blockIdx.x >> 3;
  int wgid = (xcd < 4 ? xcd * 23 : 92 + (xcd - 4) * 22) + idx;
  int bm = wgid / 9, bn = wgid % 9;

  int t = threadIdx.x;
  int w = t >> 6, lane = t & 63;
  int wm = w >> 2, wn = w & 3;          // wm: 128-row band, wn: 64-col band
  int fr = lane & 15, s16 = lane >> 4;

  const bf16_t* Ab = A  + (size_t)bm * 256 * GK;
  const bf16_t* Bb = Bt + (size_t)bn * 256 * GK;

  const int srow  = t >> 2;                              // 0..127
  const int skoff = (((t & 3) ^ ((t >> 3) & 3)) << 3);   // inverse-swizzled k-elem offset
  const int wbase = w * 512;                             // wave-uniform dest (HW adds lane*16B)

  auto stageT = [&](const bf16_t* src, int mat, int T, int s) {
    const bf16_t* g = src + (size_t)srow * GK + T * 32 + skoff;
    gload16(g,            &smem[s][mat][wbase]);
    gload16(g + 128 * GK, &smem[s][mat][4096 + wbase]);
  };
  auto rdA = [&](int s, int m) -> bf16x8 {
    int r = wm * 128 + m * 16 + fr;
    return *(const bf16x8*)(&smem[s][0][r * 32 + ((s16 ^ ((r >> 1) & 3)) << 3)]);
  };
  auto rdB = [&](int s, int n) -> bf16x8 {
    int r = wn * 64 + n * 16 + fr;
    return *(const bf16x8*)(&smem[s][1][r * 32 + ((s16 ^ ((r >> 1) & 3)) << 3)]);
  };

  f32x4 acc[8][4] = {};

  // prologue: tile 0 -> slot 0, tile 1 -> slot 1 (each wave: 8 loads)
  stageT(Ab, 0, 0, 0); stageT(Bb, 1, 0, 0);
  stageT(Ab, 0, 1, 1); stageT(Bb, 1, 1, 1);
  asm volatile("s_waitcnt vmcnt(4)" ::: "memory");   // tile 0 landed; tile 1's 4 in flight
  __builtin_amdgcn_s_barrier();

  int s = 0, s2 = 2;
  #pragma unroll 3
  for (int T = 0; T < 24; ++T) {
    const bool pf = (T <= 21);
    bf16x8 bfr[4], a0[4], a1[4];
    { // ---- q0: read B n0-3 + A m0-3; stage A(T+2); MFMA m0-3 ----
      #pragma unroll
      for (int n = 0; n < 4; n++) bfr[n] = rdB(s, n);
      #pragma unroll
      for (int m = 0; m < 4; m++) a0[m] = rdA(s, m);
      if (pf) stageT(Ab, 0, T + 2, s2);
      __builtin_amdgcn_s_setprio(1);
      #pragma unroll
      for (int m = 0; m < 4; m++)
        #pragma unroll
        for (int n = 0; n < 4; n++)
          acc[m][n] = __builtin_amdgcn_mfma_f32_16x16x32_bf16(a0[m], bfr[n], acc[m][n], 0, 0, 0);
      __builtin_amdgcn_s_setprio(0);
      __builtin_amdgcn_s_barrier();
    }
    { // ---- q1: read A m4-7; stage B(T+2); MFMA m4-7; tile-boundary wait ----
      #pragma unroll
      for (int m = 0; m < 4; m++) a1[m] = rdA(s, 4 + m);
      if (pf) stageT(Bb, 1, T + 2, s2);
      __builtin_amdgcn_s_setprio(1);
      #pragma unroll
      for (int m = 0; m < 4; m++)
        #pragma unroll
        for (int n = 0; n < 4; n++)
          acc[4 + m][n] = __builtin_amdgcn_mfma_f32_16x16x32_bf16(a1[m], bfr[n], acc[4 + m][n], 0, 0, 0);
      __builtin_amdgcn_s_setprio(0);
      if (pf)            asm volatile("s_waitcnt vmcnt(4)" ::: "memory");  // T+1 landed, T+2 in flight
      else if (T == 22)  asm volatile("s_waitcnt vmcnt(0)" ::: "memory");  // drain for last tile
      __builtin_amdgcn_s_barrier();
    }
    s  = (s  == 2) ? 0 : s  + 1;
    s2 = (s2 == 2) ? 0 : s2 + 1;
  }

  // epilogue: D layout col = lane&15, row = (lane>>4)*4 + reg; plain row-major store
  #pragma unroll
  for (int m = 0; m < 8; m++) {
    int rbase = bm * 256 + wm * 128 + m * 16 + (s16 << 2);
    #pragma unroll
    for (int n = 0; n < 4; n++) {
      int col = bn * 256 + wn * 64 + n * 16 + fr;
      float bcol = bias[col];
      float sc = (col < 768) ? 0.125f : 1.f;   // fold SCALE into q section
      f32x4 a = acc[m][n];
      #pragma unroll
      for (int r2 = 0; r2 < 4; r2++)
        qkv[(size_t)(rbase + r2) * 2304 + col] = (bf16_t)((a[r2] + bcol) * sc);
    }
  }
}

// ---------------- sparse windowed attention: 4 (b,w,h) units per 256-thr block ----------------
__global__ __launch_bounds__(256) void attn_kernel(const bf16_t* __restrict__ qkv,
                                                   bf16_t* __restrict__ ctx) {
  __shared__ float Ks[4][20][64];
  __shared__ float Vs[4][20][64];
  int tid = threadIdx.x;
  int wid = tid >> 6, lane = tid & 63;
  int id = blockIdx.x * 4 + wid;     // ((b*128 + w)*12 + h)
  int h = id % 12;
  int bw = id / 12;
  int w = bw & 127, b = bw >> 7;
  const int hc = h * 64;

  { // window-token K/V rows 0..15
    int j = lane >> 2, dd = (lane & 3) * 16;
    size_t row = (size_t)b * 2560 + w * 16 + j;
    const bf16_t* kp = qkv + row * 2304 + 768 + hc + dd;
    bf16x8 k0 = *(const bf16x8*)kp;
    bf16x8 k1 = *(const bf16x8*)(kp + 8);
    bf16x8 u0 = *(const bf16x8*)(kp + 768);
    bf16x8 u1 = *(const bf16x8*)(kp + 776);
    #pragma unroll
    for (int i = 0; i < 8; i++) {
      Ks[wid][j][dd + i] = (float)k0[i]; Ks[wid][j][dd + 8 + i] = (float)k1[i];
      Vs[wid][j][dd + i] = (float)u0[i]; Vs[wid][j][dd + 8 + i] = (float)u1[i];
    }
  }
  if (lane < 16) { // carrier K/V rows 16..19
    int j = 16 + (lane >> 2), dd = (lane & 3) * 16;
    size_t row = (size_t)b * 2560 + 2048 + w * 4 + (lane >> 2);
    const bf16_t* kp = qkv + row * 2304 + 768 + hc + dd;
    bf16x8 k0 = *(const bf16x8*)kp;
    bf16x8 k1 = *(const bf16x8*)(kp + 8);
    bf16x8 u0 = *(const bf16x8*)(kp + 768);
    bf16x8 u1 = *(const bf16x8*)(kp + 776);
    #pragma unroll
    for (int i = 0; i < 8; i++) {
      Ks[wid][j][dd + i] = (float)k0[i]; Ks[wid][j][dd + 8 + i] = (float)k1[i];
      Vs[wid][j][dd + i] = (float)u0[i]; Vs[wid][j][dd + 8 + i] = (float)u1[i];
    }
  }
  // no barrier: all consumers are in the producing wave

  int qi = lane >> 2, c4 = lane & 3, d0 = c4 * 16;
  float qreg[16];
  {
    const bf16_t* qp = qkv + ((size_t)b * 2560 + w * 16 + qi) * 2304 + hc + d0;
    bf16x8 q0 = *(const bf16x8*)qp;
    bf16x8 q1 = *(const bf16x8*)(qp + 8);
    #pragma unroll
    for (int i = 0; i < 8; i++) { qreg[i] = (float)q0[i]; qreg[8 + i] = (float)q1[i]; }
  }

  float pl[5];
  #pragma unroll
  for (int j = 0; j < 20; j++) {
    float s = 0.f;
    #pragma unroll
    for (int i = 0; i < 16; i++) s += qreg[i] * Ks[wid][j][d0 + i];
    s += __shfl_xor(s, 1);
    s += __shfl_xor(s, 2);
    if ((j & 3) == c4) pl[j >> 2] = s;
  }
  float m = fmaxf(fmaxf(fmaxf(pl[0], pl[1]), fmaxf(pl[2], pl[3])), pl[4]);
  m = fmaxf(m, __shfl_xor(m, 1));
  m = fmaxf(m, __shfl_xor(m, 2));
  float sum = 0.f;
  #pragma unroll
  for (int i = 0; i < 5; i++) { pl[i] = __expf(pl[i] - m); sum += pl[i]; }
  sum += __shfl_xor(sum, 1);
  sum += __shfl_xor(sum, 2);
  float inv = 1.f / sum;

  float acc[16] = {};
  #pragma unroll
  for (int j = 0; j < 20; j++) {
    float pj = __shfl(pl[j >> 2], (qi << 2) | (j & 3));
    #pragma unroll
    for (int i = 0; i < 16; i++) acc[i] += pj * Vs[wid][j][d0 + i];
  }

  bf16_t* cp = ctx + ((size_t)(b * 2048 + w * 16 + qi)) * 768 + hc + d0;
  #pragma unroll
  for (int i = 0; i < 16; i++) cp[i] = (bf16_t)(acc[i] * inv);
}

// ---------------- proj GEMM: 128x128 tile, BK=32, 3-slot ring, counted vmcnt (R10, verified) ----------------
__global__ __launch_bounds__(256, 1) void gemm128_proj(const bf16_t* __restrict__ A,
                                                       const bf16_t* __restrict__ Bt,
                                                       const float* __restrict__ bias,
                                                       float* __restrict__ outF) {
  __shared__ __align__(16) bf16_t smem[3][2][4096];   // [slot][A=0/B=1][r*32 + swz]

  int bm = blockIdx.x % 32;           // M = 4096 -> 32 tiles
  int bn = blockIdx.x / 32;           // N = 768  -> 6 tiles
  int t = threadIdx.x;
  int w = t >> 6, lane = t & 63;
  int wm = w >> 1, wn = w & 1;        // 2x2 waves, per-wave 64x64
  int fr = lane & 15, s16 = lane >> 4;

  const bf16_t* Ab = A  + (size_t)bm * 128 * GK;
  const bf16_t* Bb = Bt + (size_t)bn * 128 * GK;

  const int srow  = t >> 2;                              // 0..63
  const int skoff = (((t & 3) ^ ((t >> 3) & 3)) << 3);
  const int wbase = w * 512;                             // 4 waves x 512 bf16 = one 4KB line

  auto stageT = [&](const bf16_t* src, int mat, int T, int s) {
    const bf16_t* g = src + (size_t)srow * GK + T * 32 + skoff;
    gload16(g,           &smem[s][mat][wbase]);
    gload16(g + 64 * GK, &smem[s][mat][2048 + wbase]);
  };
  auto rdA = [&](int s, int m) -> bf16x8 {
    int r = wm * 64 + m * 16 + fr;
    return *(const bf16x8*)(&smem[s][0][r * 32 + ((s16 ^ ((r >> 1) & 3)) << 3)]);
  };
  auto rdB = [&](int s, int n) -> bf16x8 {
    int r = wn * 64 + n * 16 + fr;
    return *(const bf16x8*)(&smem[s][1][r * 32 + ((s16 ^ ((r >> 1) & 3)) << 3)]);
  };

  f32x4 acc[4][4] = {};

  stageT(Ab, 0, 0, 0); stageT(Bb, 1, 0, 0);
  stageT(Ab, 0, 1, 1); stageT(Bb, 1, 1, 1);
  asm volatile("s_waitcnt vmcnt(4)" ::: "memory");
  __builtin_amdgcn_s_barrier();

  int s = 0, s2 = 2;
  #pragma unroll 3
  for (int T = 0; T < 24; ++T) {
    const bool pf = (T <= 21);
    bf16x8 bfr[4], af[4];
    #pragma unroll
    for (int n = 0; n < 4; n++) bfr[n] = rdB(s, n);
    #pragma unroll
    for (int m = 0; m < 4; m++) af[m] = rdA(s, m);
    if (pf) { stageT(Ab, 0, T + 2, s2); stageT(Bb, 1, T + 2, s2); }
    __builtin_amdgcn_s_setprio(1);
    #pragma unroll
    for (int m = 0; m < 4; m++)
      #pragma unroll
      for (int n = 0; n < 4; n++)
        acc[m][n] = __builtin_amdgcn_mfma_f32_16x16x32_bf16(af[m], bfr[n], acc[m][n], 0, 0, 0);
    __builtin_amdgcn_s_setprio(0);
    if (pf)            asm volatile("s_waitcnt vmcnt(4)" ::: "memory");  // T+1 landed, T+2 in flight
    else if (T == 22)  asm volatile("s_waitcnt vmcnt(0)" ::: "memory");
    __builtin_amdgcn_s_barrier();
    s  = (s  == 2) ? 0 : s  + 1;
    s2 = (s2 == 2) ? 0 : s2 + 1;
  }

  #pragma unroll
  for (int m = 0; m < 4; m++) {
    int rbase = bm * 128 + wm * 64 + m * 16 + (s16 << 2);
    #pragma unroll
    for (int n = 0; n < 4; n++) {
      int col = bn * 128 + wn * 64 + n * 16 + fr;
      float bcol = bias[col];
      f32x4 a = acc[m][n];
      #pragma unroll
      for (int r = 0; r < 4; r++)
        outF[(size_t)(rbase + r) * 768 + col] = a[r] + bcol;
    }
  }
}

// ---------------- launch ----------------
extern "C" void kernel_launch(void* const* d_in, const int* in_sizes, int n_in,
                              void* d_out, int out_size, void* d_ws, size_t ws_size,
                              hipStream_t stream) {
  (void)in_sizes; (void)n_in; (void)out_size; (void)ws_size;
  const float* x      = (const float*)d_in[0];
  const float* W_qkv  = (const float*)d_in[1];
  const float* b_qkv  = (const float*)d_in[2];
  const float* W_car  = (const float*)d_in[3];
  const float* b_car  = (const float*)d_in[4];
  const float* W_proj = (const float*)d_in[5];
  const float* b_proj = (const float*)d_in[6];
  const float* gamma  = (const float*)d_in[7];
  const float* beta   = (const float*)d_in[8];
  float* out = (float*)d_out;

  char* ws = (char*)d_ws;
  bf16_t* wt_qkv  = (bf16_t*)(ws + OFF_WT_QKV);
  bf16_t* wt_car  = (bf16_t*)(ws + OFF_WT_CAR);
  bf16_t* wt_proj = (bf16_t*)(ws + OFF_WT_PROJ);
  bf16_t* wmean   = (bf16_t*)(ws + OFF_WMEAN);
  float*  carP    = (float*) (ws + OFF_CARP);
  bf16_t* ln      = (bf16_t*)(ws + OFF_LN);
  bf16_t* qkv     = (bf16_t*)(ws + OFF_QKV);
  bf16_t* ctx     = (bf16_t*)(ws + OFF_CTX);

  // 1. minimal prep for car: wt_car transpose + window means
  prep_small<<<832, 256, 0, stream>>>(W_car, x, wt_car, wmean);
  // 2. carrier GEMM (96 blocks) + wt_qkv/wt_proj transposes running concurrently
  car_plus<<<2400, 256, 0, stream>>>(wmean, wt_car, carP, W_qkv, W_proj, wt_qkv, wt_proj);
  // 3. LayerNorm(combined) -> bf16  (sums car partials + b_car inline)
  ln_kernel<<<5120, 192, 0, stream>>>(x, carP, b_car, gamma, beta, ln);
  // 4. QKV projection: 256^2 3-slot-ring pipelined GEMM -> plain [5120][2304] bf16
  gemm256_qkv<<<180, 512, 0, stream>>>(ln, wt_qkv, b_qkv, qkv);
  // 5. sparse windowed attention -> ctx bf16 (4 units per 256-thr block)
  attn_kernel<<<768, 256, 0, stream>>>(qkv, ctx);
  // 6. output projection: 128^2 3-slot-ring pipelined GEMM -> d_out fp32
  gemm128_proj<<<192, 256, 0, stream>>>(ctx, wt_proj, b_proj, out);
}